// Round 5
// baseline (1164.771 us; speedup 1.0000x reference)
//
#include <hip/hip_runtime.h>

#define HID 128
#define NNODE 50000
#define NEDGE 640000

typedef __attribute__((ext_vector_type(8))) short bf16x8;
typedef __attribute__((ext_vector_type(4))) float f32x4;

// ---------------------------------------------------------------- embed: x = emb[z]
static __global__ void embed_kernel(const int* __restrict__ z,
                                    const float* __restrict__ emb,
                                    float* __restrict__ x) {
  int i = blockIdx.x * 256 + threadIdx.x;
  const int total = NNODE * (HID / 4);
  if (i >= total) return;
  int node = i >> 5;
  int c = i & 31;
  ((float4*)x)[i] = ((const float4*)emb)[(size_t)z[node] * 32 + c];
}

// ---------------------------------------------------------------- CSR build
static __global__ void hist_kernel(const int* __restrict__ dst, int* __restrict__ deg) {
  int i = blockIdx.x * 256 + threadIdx.x;
  if (i < NEDGE) atomicAdd(&deg[dst[i]], 1);
}

static __global__ void scan_kernel(const int* __restrict__ deg,
                                   int* __restrict__ row_ptr,
                                   int* __restrict__ cursor) {
  __shared__ int sums[1024];
  int t = threadIdx.x;
  const int per = (NNODE + 1023) / 1024;
  int base = t * per;
  int s = 0;
  for (int i = 0; i < per; ++i) {
    int idx = base + i;
    if (idx < NNODE) s += deg[idx];
  }
  sums[t] = s;
  __syncthreads();
  for (int off = 1; off < 1024; off <<= 1) {
    int v = (t >= off) ? sums[t - off] : 0;
    __syncthreads();
    if (t >= off) sums[t] += v;
    __syncthreads();
  }
  int run = (t == 0) ? 0 : sums[t - 1];
  for (int i = 0; i < per; ++i) {
    int idx = base + i;
    if (idx < NNODE) {
      row_ptr[idx] = run;
      cursor[idx] = run;
      run += deg[idx];
    }
  }
  if (t == 1023) row_ptr[NNODE] = run;
}

static __global__ void fill_kernel(const int* __restrict__ src, const int* __restrict__ dst,
                                   int* __restrict__ cursor, int2* __restrict__ elist) {
  int i = blockIdx.x * 256 + threadIdx.x;
  if (i < NEDGE) {
    int d = dst[i];
    int p = atomicAdd(&cursor[d], 1);
    elist[p] = make_int2(i, src[i]);
  }
}

// ---------------------------------------------------------------- permute (once/call):
// ea_perm[p] = ea[eid(p)]  (random 512B read once; all convs then read streaming)
// src_perm[p] = src(p)
static __global__ void permute_kernel(const float* __restrict__ ea,
                                      const int2* __restrict__ elist,
                                      int* __restrict__ srcp,
                                      float* __restrict__ eap) {
  int t = blockIdx.x * 256 + threadIdx.x;          // one float4 segment each
  const int total = NEDGE * 32;
  if (t >= total) return;
  int j = t >> 5, seg = t & 31;
  int2 es = elist[j];
  float4 v = ((const float4*)ea)[(size_t)es.x * 32 + seg];
  ((float4*)eap)[(size_t)j * 32 + seg] = v;
  if (seg == 0) srcp[j] = es.y;
}

// ---------------------------------------------------------------- gather:
// out[n] = x[n] + sum_{e->n} relu(x[src]+ea_perm[e]);  1 node/wave, unroll x8.
// ea_perm reads are sequential (NT); only x-gathers are random (L2/L3-resident).
static __global__ __launch_bounds__(256) void gather_kernel(
    const float* __restrict__ x, const float* __restrict__ eap,
    const int* __restrict__ row_ptr, const int* __restrict__ srcp,
    float* __restrict__ out) {
  int wave = threadIdx.x >> 6;
  int lane = threadIdx.x & 63;
  int node = blockIdx.x * 4 + wave;
  if (node >= NNODE) return;
  const float2* x2 = (const float2*)x;
  const double* ed = (const double*)eap;           // 8B NT loads
  float2 a0 = x2[(size_t)node * 64 + lane];
  float2 a1 = make_float2(0.f, 0.f);
  float2 a2 = make_float2(0.f, 0.f);
  float2 a3 = make_float2(0.f, 0.f);
  int j  = row_ptr[node];
  int je = row_ptr[node + 1];
  for (; j + 8 <= je; j += 8) {
    // ea loads: addresses independent of srcp -> issue immediately, sequential
    double d0 = __builtin_nontemporal_load(&ed[(size_t)(j + 0) * 64 + lane]);
    double d1 = __builtin_nontemporal_load(&ed[(size_t)(j + 1) * 64 + lane]);
    double d2 = __builtin_nontemporal_load(&ed[(size_t)(j + 2) * 64 + lane]);
    double d3 = __builtin_nontemporal_load(&ed[(size_t)(j + 3) * 64 + lane]);
    double d4 = __builtin_nontemporal_load(&ed[(size_t)(j + 4) * 64 + lane]);
    double d5 = __builtin_nontemporal_load(&ed[(size_t)(j + 5) * 64 + lane]);
    double d6 = __builtin_nontemporal_load(&ed[(size_t)(j + 6) * 64 + lane]);
    double d7 = __builtin_nontemporal_load(&ed[(size_t)(j + 7) * 64 + lane]);
    int s0 = srcp[j + 0], s1 = srcp[j + 1], s2 = srcp[j + 2], s3 = srcp[j + 3];
    int s4 = srcp[j + 4], s5 = srcp[j + 5], s6 = srcp[j + 6], s7 = srcp[j + 7];
    float2 xv0 = x2[(size_t)s0 * 64 + lane];
    float2 xv1 = x2[(size_t)s1 * 64 + lane];
    float2 xv2 = x2[(size_t)s2 * 64 + lane];
    float2 xv3 = x2[(size_t)s3 * 64 + lane];
    float2 xv4 = x2[(size_t)s4 * 64 + lane];
    float2 xv5 = x2[(size_t)s5 * 64 + lane];
    float2 xv6 = x2[(size_t)s6 * 64 + lane];
    float2 xv7 = x2[(size_t)s7 * 64 + lane];
    float2 e0 = *(float2*)&d0, e1 = *(float2*)&d1, e2 = *(float2*)&d2, e3 = *(float2*)&d3;
    float2 e4 = *(float2*)&d4, e5 = *(float2*)&d5, e6 = *(float2*)&d6, e7 = *(float2*)&d7;
    a0.x += fmaxf(xv0.x + e0.x, 0.f); a0.y += fmaxf(xv0.y + e0.y, 0.f);
    a1.x += fmaxf(xv1.x + e1.x, 0.f); a1.y += fmaxf(xv1.y + e1.y, 0.f);
    a2.x += fmaxf(xv2.x + e2.x, 0.f); a2.y += fmaxf(xv2.y + e2.y, 0.f);
    a3.x += fmaxf(xv3.x + e3.x, 0.f); a3.y += fmaxf(xv3.y + e3.y, 0.f);
    a0.x += fmaxf(xv4.x + e4.x, 0.f); a0.y += fmaxf(xv4.y + e4.y, 0.f);
    a1.x += fmaxf(xv5.x + e5.x, 0.f); a1.y += fmaxf(xv5.y + e5.y, 0.f);
    a2.x += fmaxf(xv6.x + e6.x, 0.f); a2.y += fmaxf(xv6.y + e6.y, 0.f);
    a3.x += fmaxf(xv7.x + e7.x, 0.f); a3.y += fmaxf(xv7.y + e7.y, 0.f);
  }
  for (; j < je; ++j) {
    double d0 = __builtin_nontemporal_load(&ed[(size_t)j * 64 + lane]);
    int s0 = srcp[j];
    float2 xv = x2[(size_t)s0 * 64 + lane];
    float2 ev = *(float2*)&d0;
    a0.x += fmaxf(xv.x + ev.x, 0.f);
    a0.y += fmaxf(xv.y + ev.y, 0.f);
  }
  a0.x += a1.x + a2.x + a3.x;
  a0.y += a1.y + a2.y + a3.y;
  ((float2*)out)[(size_t)node * 64 + lane] = a0;
}

// ---------------------------------------------------------------- W split (once/call):
// Wt[hi|lo][c*2+g][n][136 k] bf16 (transposed so B-frag reads 8 consecutive k)
static __global__ void wsplit_kernel(const float* __restrict__ W1, const float* __restrict__ W2,
                                     unsigned short* __restrict__ whi,
                                     unsigned short* __restrict__ wlo) {
  int idx = blockIdx.x * 256 + threadIdx.x;
  if (idx >= 6 * 16384) return;
  int cg = idx >> 14;
  int rem = idx & 16383;
  int k = rem >> 7, n = rem & 127;
  int c = cg >> 1, g = cg & 1;
  float v = (g ? W2 : W1)[c * 16384 + k * 128 + n];
  unsigned u = __float_as_uint(v);
  unsigned hb = u >> 16;
  float hf = __uint_as_float(hb << 16);
  unsigned lb = __float_as_uint(v - hf) >> 16;
  int o = cg * 17408 + n * 136 + k;
  whi[o] = (unsigned short)hb;
  wlo[o] = (unsigned short)lb;
}

// ---------------------------------------------------------------- MFMA MLP (unchanged from R4)
static __global__ __launch_bounds__(256) void mlp_mfma(
    const float* __restrict__ in, const float* __restrict__ xres,
    const unsigned short* __restrict__ wt1hi, const unsigned short* __restrict__ wt1lo,
    const unsigned short* __restrict__ wt2hi, const unsigned short* __restrict__ wt2lo,
    const float* __restrict__ b1, const float* __restrict__ b2,
    float* __restrict__ xout, int relu_out) {
  __shared__ unsigned short WbHi[128 * 72];
  __shared__ unsigned short WbLo[128 * 72];
  __shared__ float Ts[64 * 132];
  const int tid = threadIdx.x;
  const int w = tid >> 6, l = tid & 63;
  const int lm = l & 15, quad = l >> 4;
  const int row0 = blockIdx.x * 64;

  float b1v[8], b2v[8];
#pragma unroll
  for (int t = 0; t < 8; ++t) { b1v[t] = b1[t * 16 + lm]; b2v[t] = b2[t * 16 + lm]; }

  f32x4 acc[8];
#pragma unroll
  for (int t = 0; t < 8; ++t) acc[t] = (f32x4){0.f, 0.f, 0.f, 0.f};

  int arow = row0 + w * 16 + lm;
  if (arow >= NNODE) arow = NNODE - 1;

  // ---- GEMM 1: acc = in @ W1
  for (int kc = 0; kc < 128; kc += 64) {
    __syncthreads();
    for (int idx = tid; idx < 128 * 8; idx += 256) {
      int n = idx >> 3, seg = idx & 7;
      *(uint4*)&WbHi[n * 72 + seg * 8] = *(const uint4*)&wt1hi[n * 136 + kc + seg * 8];
      *(uint4*)&WbLo[n * 72 + seg * 8] = *(const uint4*)&wt1lo[n * 136 + kc + seg * 8];
    }
    __syncthreads();
#pragma unroll
    for (int ks = 0; ks < 64; ks += 32) {
      const float* ap = in + (size_t)arow * 128 + kc + ks + quad * 8;
      float4 av0 = *(const float4*)ap;
      float4 av1 = *(const float4*)(ap + 4);
      float av[8] = {av0.x, av0.y, av0.z, av0.w, av1.x, av1.y, av1.z, av1.w};
      bf16x8 ah, al;
#pragma unroll
      for (int jj = 0; jj < 8; ++jj) {
        unsigned u = __float_as_uint(av[jj]);
        unsigned hb = u >> 16;
        float hf = __uint_as_float(hb << 16);
        unsigned lb = __float_as_uint(av[jj] - hf) >> 16;
        ah[jj] = (short)hb; al[jj] = (short)lb;
      }
#pragma unroll
      for (int t = 0; t < 8; ++t) {
        int off = (t * 16 + lm) * 72 + ks + quad * 8;
        bf16x8 bh = *(const bf16x8*)&WbHi[off];
        bf16x8 bl = *(const bf16x8*)&WbLo[off];
        acc[t] = __builtin_amdgcn_mfma_f32_16x16x32_bf16(ah, bh, acc[t], 0, 0, 0);
        acc[t] = __builtin_amdgcn_mfma_f32_16x16x32_bf16(ah, bl, acc[t], 0, 0, 0);
        acc[t] = __builtin_amdgcn_mfma_f32_16x16x32_bf16(al, bh, acc[t], 0, 0, 0);
      }
    }
  }
  __syncthreads();

#pragma unroll
  for (int t = 0; t < 8; ++t)
#pragma unroll
    for (int r = 0; r < 4; ++r)
      Ts[(w * 16 + quad * 4 + r) * 132 + t * 16 + lm] = fmaxf(acc[t][r] + b1v[t], 0.f);

#pragma unroll
  for (int t = 0; t < 8; ++t) acc[t] = (f32x4){0.f, 0.f, 0.f, 0.f};
  __syncthreads();

  // ---- GEMM 2: acc = t @ W2
  for (int kc = 0; kc < 128; kc += 64) {
    __syncthreads();
    for (int idx = tid; idx < 128 * 8; idx += 256) {
      int n = idx >> 3, seg = idx & 7;
      *(uint4*)&WbHi[n * 72 + seg * 8] = *(const uint4*)&wt2hi[n * 136 + kc + seg * 8];
      *(uint4*)&WbLo[n * 72 + seg * 8] = *(const uint4*)&wt2lo[n * 136 + kc + seg * 8];
    }
    __syncthreads();
#pragma unroll
    for (int ks = 0; ks < 64; ks += 32) {
      const float* tp = &Ts[(w * 16 + lm) * 132 + kc + ks + quad * 8];
      float4 av0 = *(const float4*)tp;
      float4 av1 = *(const float4*)(tp + 4);
      float av[8] = {av0.x, av0.y, av0.z, av0.w, av1.x, av1.y, av1.z, av1.w};
      bf16x8 ah, al;
#pragma unroll
      for (int jj = 0; jj < 8; ++jj) {
        unsigned u = __float_as_uint(av[jj]);
        unsigned hb = u >> 16;
        float hf = __uint_as_float(hb << 16);
        unsigned lb = __float_as_uint(av[jj] - hf) >> 16;
        ah[jj] = (short)hb; al[jj] = (short)lb;
      }
#pragma unroll
      for (int t = 0; t < 8; ++t) {
        int off = (t * 16 + lm) * 72 + ks + quad * 8;
        bf16x8 bh = *(const bf16x8*)&WbHi[off];
        bf16x8 bl = *(const bf16x8*)&WbLo[off];
        acc[t] = __builtin_amdgcn_mfma_f32_16x16x32_bf16(ah, bh, acc[t], 0, 0, 0);
        acc[t] = __builtin_amdgcn_mfma_f32_16x16x32_bf16(ah, bl, acc[t], 0, 0, 0);
        acc[t] = __builtin_amdgcn_mfma_f32_16x16x32_bf16(al, bh, acc[t], 0, 0, 0);
      }
    }
  }

#pragma unroll
  for (int t = 0; t < 8; ++t) {
#pragma unroll
    for (int r = 0; r < 4; ++r) {
      int row = row0 + w * 16 + quad * 4 + r;
      if (row < NNODE) {
        int col = t * 16 + lm;
        float v = acc[t][r] + b2v[t];
        if (relu_out) v = fmaxf(v, 0.f);
        v += xres[(size_t)row * 128 + col];
        xout[(size_t)row * 128 + col] = v;
      }
    }
  }
}

extern "C" void kernel_launch(void* const* d_in, const int* in_sizes, int n_in,
                              void* d_out, int out_size, void* d_ws, size_t ws_size,
                              hipStream_t stream) {
  const int*   z   = (const int*)d_in[0];
  const int*   ei  = (const int*)d_in[1];
  const float* ea  = (const float*)d_in[2];
  const float* emb = (const float*)d_in[3];
  const float* W1  = (const float*)d_in[4];
  const float* b1  = (const float*)d_in[5];
  const float* W2  = (const float*)d_in[6];
  const float* b2  = (const float*)d_in[7];
  float* outp = (float*)d_out;

  char* ws = (char*)d_ws;
  float* xbuf   = (float*)(ws + 0);                        // 25.6 MB
  float* obuf   = (float*)(ws + 25600000);                 // 25.6 MB
  int*   deg    = (int*)  (ws + 51200000);
  int*   cursor = (int*)  (ws + 51400000);
  int*   rowptr = (int*)  (ws + 51600000);
  int2*  elist  = (int2*) (ws + 51800016);                 // 5.12 MB
  unsigned short* whi = (unsigned short*)(ws + 57000000);  // 208,896 B
  unsigned short* wlo = (unsigned short*)(ws + 57250000);  // 208,896 B
  int*   srcp   = (int*)  (ws + 57500000);                 // 2.56 MB
  float* eaperm = (float*)(ws + 60100000);                 // 327.68 MB (end ~388 MB; ws = 1.31 GB)

  const int* srcv = ei;
  const int* dstv = ei + NEDGE;

  hipMemsetAsync(deg, 0, NNODE * sizeof(int), stream);
  embed_kernel<<<(NNODE * 32 + 255) / 256, 256, 0, stream>>>(z, emb, xbuf);
  hist_kernel<<<(NEDGE + 255) / 256, 256, 0, stream>>>(dstv, deg);
  scan_kernel<<<1, 1024, 0, stream>>>(deg, rowptr, cursor);
  fill_kernel<<<(NEDGE + 255) / 256, 256, 0, stream>>>(srcv, dstv, cursor, elist);
  permute_kernel<<<(NEDGE * 32) / 256, 256, 0, stream>>>(ea, elist, srcp, eaperm);
  wsplit_kernel<<<(6 * 16384 + 255) / 256, 256, 0, stream>>>(W1, W2, whi, wlo);

  for (int i = 0; i < 3; ++i) {
    gather_kernel<<<(NNODE + 3) / 4, 256, 0, stream>>>(xbuf, eaperm, rowptr, srcp, obuf);
    float* xo = (i == 2) ? outp : xbuf;
    mlp_mfma<<<(NNODE + 63) / 64, 256, 0, stream>>>(
        obuf, xbuf,
        whi + (size_t)(i * 2 + 0) * 17408, wlo + (size_t)(i * 2 + 0) * 17408,
        whi + (size_t)(i * 2 + 1) * 17408, wlo + (size_t)(i * 2 + 1) * 17408,
        b1 + (size_t)i * HID, b2 + (size_t)i * HID,
        xo, (i < 2) ? 1 : 0);
  }
}